// Round 12
// baseline (281.590 us; speedup 1.0000x reference)
//
#include <hip/hip_runtime.h>
#include <cstddef>

#define NN 100000
#define NE 600000
#define HID 128

typedef _Float16 half8 __attribute__((ext_vector_type(8)));
typedef _Float16 half2v __attribute__((ext_vector_type(2)));
typedef float f32x4 __attribute__((ext_vector_type(4)));

union H8 { _Float16 h[8]; half2v p[4]; uint4 u; half8 v; };

// shared accumulate helper: accf[0..7] += 8 f16 lanes of hh
__device__ __forceinline__ void acc8(const H8& hh, float* accf) {
#if __has_builtin(__builtin_amdgcn_fdot2)
    const half2v selx = {(_Float16)1.0f, (_Float16)0.0f};
    const half2v sely = {(_Float16)0.0f, (_Float16)1.0f};
    #pragma unroll
    for (int p = 0; p < 4; ++p) {
        accf[2*p]   = __builtin_amdgcn_fdot2(hh.p[p], selx, accf[2*p],   false);
        accf[2*p+1] = __builtin_amdgcn_fdot2(hh.p[p], sely, accf[2*p+1], false);
    }
#else
    #pragma unroll
    for (int j = 0; j < 8; ++j) accf[j] += (float)hh.h[j];
#endif
}

// ---------------------------------------------------------------- degree (int)
__global__ void k_degi(const int* __restrict__ col, int* __restrict__ degi, int E) {
    int e = blockIdx.x * blockDim.x + threadIdx.x;
    if (e < E) atomicAdd(&degi[col[e]], 1);
}

// ---------------------------------------------------------------- W -> WT f16
__global__ void k_wprep(const float* __restrict__ W1, const float* __restrict__ W2,
                        const float* __restrict__ W3, _Float16* __restrict__ wt) {
    int b = blockIdx.x;            // 0..383
    int layer = b >> 7, k = b & 127;
    const float* W = layer == 0 ? W1 : (layer == 1 ? W2 : W3);
    int c = threadIdx.x;           // 0..127
    wt[((size_t)layer << 14) + c * 128 + k] = (_Float16)W[k * 128 + c];
}

// ---------------------------------------------------------------- prefix scan
__global__ void k_blocksum(const int* __restrict__ degi, float* __restrict__ dinv,
                           int* __restrict__ bsum, int N) {
    __shared__ int sh[256];
    int i = blockIdx.x * 256 + threadIdx.x;
    int v = i < N ? degi[i] : 0;
    if (i < N) dinv[i] = v > 0 ? rsqrtf((float)v) : 0.0f;
    sh[threadIdx.x] = v;
    __syncthreads();
    for (int s = 128; s > 0; s >>= 1) {
        if (threadIdx.x < s) sh[threadIdx.x] += sh[threadIdx.x + s];
        __syncthreads();
    }
    if (threadIdx.x == 0) bsum[blockIdx.x] = sh[0];
}

__global__ void k_scan_bsum(int* __restrict__ bsum, int nb) {
    __shared__ int sh[512];
    int tid = threadIdx.x;
    int v = (tid < nb) ? bsum[tid] : 0;
    sh[tid] = v;
    __syncthreads();
    #pragma unroll
    for (int s = 1; s < 512; s <<= 1) {
        int t = (tid >= s) ? sh[tid - s] : 0;
        __syncthreads();
        sh[tid] += t;
        __syncthreads();
    }
    if (tid < nb) bsum[tid] = sh[tid] - v;   // exclusive
}

__global__ void k_scan_apply(const int* __restrict__ degi, const int* __restrict__ bsum,
                             int* __restrict__ rowptr, int* __restrict__ cursor, int N) {
    __shared__ int sh[256];
    int i = blockIdx.x * 256 + threadIdx.x;
    int v = (i < N) ? degi[i] : 0;
    sh[threadIdx.x] = v;
    __syncthreads();
    #pragma unroll
    for (int s = 1; s < 256; s <<= 1) {
        int t = (threadIdx.x >= s) ? sh[threadIdx.x - s] : 0;
        __syncthreads();
        sh[threadIdx.x] += t;
        __syncthreads();
    }
    if (i < N) {
        int excl = bsum[blockIdx.x] + sh[threadIdx.x] - v;
        rowptr[i] = excl;
        cursor[i] = excl;
        if (i == N - 1) rowptr[N] = bsum[blockIdx.x] + sh[threadIdx.x];
    }
}

// csr_off stores BYTE offset of the source row (src * HID * 2, fits int32)
__global__ void k_fill_csr(const int* __restrict__ row, const int* __restrict__ col,
                           int* __restrict__ cursor, int* __restrict__ csr_off, int E) {
    int e = blockIdx.x * blockDim.x + threadIdx.x;
    if (e >= E) return;
    int r = row[e], c = col[e];
    int pos = atomicAdd(&cursor[c], 1);
    csr_off[pos] = r * (HID * 2);
}

// ---------------------------------------------------------------- MFMA GEMM (layer 1)
// H[r] (f16) = dinv[r] * (A[r] @ W)
__global__ __launch_bounds__(256, 2) void k_gemm(
    const float* __restrict__ A, const _Float16* __restrict__ WT,
    const float* __restrict__ dinv, _Float16* __restrict__ H, int nrows)
{
    __shared__ _Float16 asl[128 * 128];   // 32 KB
    __shared__ _Float16 wsl[128 * 128];   // 32 KB
    const int tid  = threadIdx.x;
    const int lane = tid & 63;
    const int w    = tid >> 6;
    const int wm   = w >> 1, wn = w & 1;
    const int ln15 = lane & 15;
    const int hi   = lane >> 4;           // 0..3
    const int row0 = blockIdx.x * 128;

    #pragma unroll
    for (int i = 0; i < 8; ++i) {
        int g = i * 256 + tid;
        int c = g >> 4, k8 = (g & 15) << 3;
        uint4 wv = *(const uint4*)(WT + c * 128 + k8);
        *(uint4*)&wsl[c * 128 + (k8 ^ ((c & 7) << 3))] = wv;
    }
    #pragma unroll
    for (int i = 0; i < 8; ++i) {
        int g = i * 256 + tid;
        int r = g >> 4, c8 = (g & 15) << 3;
        int gr = row0 + r; if (gr >= nrows) gr = nrows - 1;
        const float4* src = (const float4*)(A + (size_t)gr * HID + c8);
        float4 v0 = src[0], v1 = src[1];
        H8 o;
        o.h[0] = (_Float16)v0.x; o.h[1] = (_Float16)v0.y;
        o.h[2] = (_Float16)v0.z; o.h[3] = (_Float16)v0.w;
        o.h[4] = (_Float16)v1.x; o.h[5] = (_Float16)v1.y;
        o.h[6] = (_Float16)v1.z; o.h[7] = (_Float16)v1.w;
        *(uint4*)&asl[r * 128 + (c8 ^ ((r & 7) << 3))] = o.u;
    }
    __syncthreads();

    f32x4 acc[4][4];
    #pragma unroll
    for (int i = 0; i < 4; ++i)
        #pragma unroll
        for (int j = 0; j < 4; ++j) {
            acc[i][j][0] = 0.0f; acc[i][j][1] = 0.0f;
            acc[i][j][2] = 0.0f; acc[i][j][3] = 0.0f;
        }

    #pragma unroll
    for (int ks = 0; ks < 4; ++ks) {
        const int k0 = ks * 32 + hi * 8;
        half8 a[4], b[4];
        #pragma unroll
        for (int i = 0; i < 4; ++i) {
            int ra = wm * 64 + i * 16 + ln15;
            a[i] = *(const half8*)&asl[ra * 128 + (k0 ^ ((ra & 7) << 3))];
            int cb = wn * 64 + i * 16 + ln15;
            b[i] = *(const half8*)&wsl[cb * 128 + (k0 ^ ((cb & 7) << 3))];
        }
        #pragma unroll
        for (int i = 0; i < 4; ++i)
            #pragma unroll
            for (int j = 0; j < 4; ++j)
                acc[i][j] = __builtin_amdgcn_mfma_f32_16x16x32_f16(a[i], b[j], acc[i][j], 0, 0, 0);
    }

    #pragma unroll
    for (int i = 0; i < 4; ++i) {
        #pragma unroll
        for (int q = 0; q < 4; ++q) {
            int r = row0 + wm * 64 + i * 16 + hi * 4 + q;
            if (r < nrows) {
                float s = dinv[r];
                #pragma unroll
                for (int j = 0; j < 4; ++j) {
                    H[(size_t)r * HID + wn * 64 + j * 16 + ln15] =
                        (_Float16)(acc[i][j][q] * s);
                }
            }
        }
    }
}

// ---------------------------------------------------------------- fused agg+GEMM (512 thr)
__global__ __launch_bounds__(512, 2) void k_gemm_agg(
    const _Float16* __restrict__ hprev, const int* __restrict__ csr_off,
    const int* __restrict__ rowptr, const float* __restrict__ dinv,
    const float* __restrict__ bias, const _Float16* __restrict__ WT,
    _Float16* __restrict__ H, int nrows)
{
    __shared__ _Float16 asl[128 * 128];   // 32 KB
    __shared__ _Float16 wsl[128 * 128];   // 32 KB
    __shared__ int s_ptr[129];
    const int tid  = threadIdx.x;
    const int lane = tid & 63;
    const int w    = tid >> 6;            // 0..7
    const int row0 = blockIdx.x * 128;

    if (tid < 129) {
        int n = row0 + tid; if (n > nrows) n = nrows;
        s_ptr[tid] = rowptr[n];
    }
    #pragma unroll
    for (int i = 0; i < 4; ++i) {
        int g = i * 512 + tid;
        int c = g >> 4, k8 = (g & 15) << 3;
        uint4 wv = *(const uint4*)(WT + c * 128 + k8);
        *(uint4*)&wsl[c * 128 + (k8 ^ ((c & 7) << 3))] = wv;
    }
    __syncthreads();

    const int es = lane >> 4;          // 0..3 edge slot (HIGH bits)
    const int fg = lane & 15;          // feature group
    const char* hb = (const char*)hprev;
    const int f0 = fg * 8 + es * 2;
    const float2 bv = *(const float2*)(bias + f0);
    const uint4 z = make_uint4(0, 0, 0, 0);

    #pragma unroll 2
    for (int t = 0; t < 16; ++t) {
        const int ni  = (w << 4) + t;
        const int beg = s_ptr[ni], end = s_ptr[ni + 1];

        float accf[8];
        #pragma unroll
        for (int j = 0; j < 8; ++j) accf[j] = 0.0f;

        int nr  = (end - beg + 3) >> 2;
        int idx = beg + es;
        int r   = 0;
        for (; r + 1 < nr; r += 2, idx += 8) {
            int o0 = (idx     < end) ? csr_off[idx]     : -1;
            int o1 = (idx + 4 < end) ? csr_off[idx + 4] : -1;
            uint4 u0 = (o0 >= 0) ? *(const uint4*)(hb + (size_t)(unsigned)o0 + fg * 16) : z;
            uint4 u1 = (o1 >= 0) ? *(const uint4*)(hb + (size_t)(unsigned)o1 + fg * 16) : z;
            H8 h0; h0.u = u0;
            H8 h1; h1.u = u1;
            acc8(h0, accf);
            acc8(h1, accf);
        }
        if (r < nr) {
            int o0 = (idx < end) ? csr_off[idx] : -1;
            uint4 u0 = (o0 >= 0) ? *(const uint4*)(hb + (size_t)(unsigned)o0 + fg * 16) : z;
            H8 h0; h0.u = u0;
            acc8(h0, accf);
        }

        #pragma unroll
        for (int j = 0; j < 8; ++j) {
            accf[j] += __shfl_xor(accf[j], 16);
            accf[j] += __shfl_xor(accf[j], 32);
        }

        float v0 = es < 2 ? (es == 0 ? accf[0] : accf[2])
                          : (es == 2 ? accf[4] : accf[6]);
        float v1 = es < 2 ? (es == 0 ? accf[1] : accf[3])
                          : (es == 2 ? accf[5] : accf[7]);
        int node = row0 + ni;
        float s = (node < nrows) ? dinv[node] : 0.0f;
        union { _Float16 h[2]; unsigned u; } o;
        o.h[0] = (_Float16)fmaxf(v0 * s + bv.x, 0.0f);
        o.h[1] = (_Float16)fmaxf(v1 * s + bv.y, 0.0f);
        *(unsigned*)&asl[ni * 128 + (((unsigned)(fg * 8)) ^ ((ni & 7) << 3)) + es * 2] = o.u;
    }
    __syncthreads();

    const int wm   = w >> 1, wn = w & 1;
    const int ln15 = lane & 15;
    const int hi   = lane >> 4;

    f32x4 acc[2][4];
    #pragma unroll
    for (int i = 0; i < 2; ++i)
        #pragma unroll
        for (int j = 0; j < 4; ++j) {
            acc[i][j][0] = 0.0f; acc[i][j][1] = 0.0f;
            acc[i][j][2] = 0.0f; acc[i][j][3] = 0.0f;
        }

    #pragma unroll
    for (int ks = 0; ks < 4; ++ks) {
        const int k0 = ks * 32 + hi * 8;
        half8 a[2], b[4];
        #pragma unroll
        for (int i = 0; i < 2; ++i) {
            int ra = wm * 32 + i * 16 + ln15;
            a[i] = *(const half8*)&asl[ra * 128 + (k0 ^ ((ra & 7) << 3))];
        }
        #pragma unroll
        for (int j = 0; j < 4; ++j) {
            int cb = wn * 64 + j * 16 + ln15;
            b[j] = *(const half8*)&wsl[cb * 128 + (k0 ^ ((cb & 7) << 3))];
        }
        #pragma unroll
        for (int i = 0; i < 2; ++i)
            #pragma unroll
            for (int j = 0; j < 4; ++j)
                acc[i][j] = __builtin_amdgcn_mfma_f32_16x16x32_f16(a[i], b[j], acc[i][j], 0, 0, 0);
    }

    #pragma unroll
    for (int i = 0; i < 2; ++i) {
        #pragma unroll
        for (int q = 0; q < 4; ++q) {
            int r = row0 + wm * 32 + i * 16 + hi * 4 + q;
            if (r < nrows) {
                float s = dinv[r];
                #pragma unroll
                for (int j = 0; j < 4; ++j) {
                    H[(size_t)r * HID + wn * 64 + j * 16 + ln15] =
                        (_Float16)(acc[i][j][q] * s);
                }
            }
        }
    }
}

// ---------------------------------------------------------------- final aggregate, feature-half
// out[node][HALF*64 + 0..63] = dinv[node]*sum(hprev[src][...]) + b3[...]
// lane = es*8 + fg (es 0..7 edge slots HIGH, fg 0..7): quarter-wave = 2
// contiguous 128B half-rows; one wave instr covers 8 edges (1 KB).
// Fold es via shfl_xor(8,16,32); es==0 lanes (fg=0..7) store 8 f32 each ->
// 256B contiguous per node. Working set per dispatch = 12.8 MB (L2-capacity probe).
template <int HALF>
__global__ __launch_bounds__(256) void k_aggregate_h(
    const _Float16* __restrict__ hs, const int* __restrict__ csr_off,
    const int* __restrict__ rowptr, const float* __restrict__ dinv,
    const float* __restrict__ bias, float* __restrict__ out, int N)
{
    constexpr int NB = 32;
    constexpr int CAP = 2048;
    __shared__ int s_off[CAP + 16];
    __shared__ int s_ptr[NB + 1];

    const int tid = threadIdx.x;
    const int n0  = blockIdx.x * NB;   // 3125 * 32 == 100000 exactly
    if (tid <= NB) s_ptr[tid] = rowptr[n0 + tid];
    __syncthreads();
    const int Rbeg = s_ptr[0];
    const int cnt  = s_ptr[NB] - Rbeg;
    const bool fast = cnt <= CAP;
    if (fast) {
        for (int i = tid; i < cnt; i += 256) s_off[i] = csr_off[Rbeg + i];
    }
    __syncthreads();
    const int* offp = fast ? (const int*)s_off : (csr_off + Rbeg);

    const int lane = tid & 63;
    const int w    = tid >> 6;
    const int es   = lane >> 3;        // 0..7 edge slot (HIGH bits)
    const int fg   = lane & 7;         // feature group (8 f16 = 16 B)
    const char* hb = (const char*)hs;
    const int fbyte = HALF * 128 + fg * 16;
    // bias for es==0 store path: features HALF*64 + fg*8 .. +7
    const float4 b0 = *(const float4*)(bias + HALF * 64 + fg * 8);
    const float4 b1 = *(const float4*)(bias + HALF * 64 + fg * 8 + 4);
    const uint4 z = make_uint4(0, 0, 0, 0);

    #pragma unroll 2
    for (int t = 0; t < 8; ++t) {
        const int ni   = (w << 3) + t;
        const int node = n0 + ni;
        const int beg  = s_ptr[ni] - Rbeg;
        const int end  = s_ptr[ni + 1] - Rbeg;

        float accf[8];
        #pragma unroll
        for (int j = 0; j < 8; ++j) accf[j] = 0.0f;

        int nr  = (end - beg + 7) >> 3;
        int idx = beg + es;
        int r   = 0;
        for (; r + 1 < nr; r += 2, idx += 16) {
            int o0 = (idx     < end) ? offp[idx]     : -1;
            int o1 = (idx + 8 < end) ? offp[idx + 8] : -1;
            uint4 u0 = (o0 >= 0) ? *(const uint4*)(hb + (size_t)(unsigned)o0 + fbyte) : z;
            uint4 u1 = (o1 >= 0) ? *(const uint4*)(hb + (size_t)(unsigned)o1 + fbyte) : z;
            H8 h0; h0.u = u0;
            H8 h1; h1.u = u1;
            acc8(h0, accf);
            acc8(h1, accf);
        }
        if (r < nr) {
            int o0 = (idx < end) ? offp[idx] : -1;
            uint4 u0 = (o0 >= 0) ? *(const uint4*)(hb + (size_t)(unsigned)o0 + fbyte) : z;
            H8 h0; h0.u = u0;
            acc8(h0, accf);
        }

        // fold the 8 edge slots
        #pragma unroll
        for (int j = 0; j < 8; ++j) {
            accf[j] += __shfl_xor(accf[j], 8);
            accf[j] += __shfl_xor(accf[j], 16);
            accf[j] += __shfl_xor(accf[j], 32);
        }

        if (es == 0) {   // lanes 0..7: fg-th 8-feature group -> 32 B each, 256 B/node
            float s = dinv[node];
            float4 o0 = make_float4(accf[0] * s + b0.x, accf[1] * s + b0.y,
                                    accf[2] * s + b0.z, accf[3] * s + b0.w);
            float4 o1 = make_float4(accf[4] * s + b1.x, accf[5] * s + b1.y,
                                    accf[6] * s + b1.z, accf[7] * s + b1.w);
            float* dst = out + (size_t)node * HID + HALF * 64 + fg * 8;
            *(float4*)dst       = o0;
            *(float4*)(dst + 4) = o1;
        }
    }
}

// ---------------------------------------------------------------- launch
extern "C" void kernel_launch(void* const* d_in, const int* in_sizes, int n_in,
                              void* d_out, int out_size, void* d_ws, size_t ws_size,
                              hipStream_t stream)
{
    const float* x  = (const float*)d_in[0];
    const float* W1 = (const float*)d_in[1];
    const float* b1 = (const float*)d_in[2];
    const float* W2 = (const float*)d_in[3];
    const float* b2 = (const float*)d_in[4];
    const float* W3 = (const float*)d_in[5];
    const float* b3 = (const float*)d_in[6];
    const int*   ei = (const int*)d_in[7];
    const int* row  = ei;            // sources
    const int* colv = ei + NE;       // targets
    float* out = (float*)d_out;

    _Float16* hA  = (_Float16*)d_ws;                  // NN*HID
    _Float16* hB  = hA + (size_t)NN * HID;            // NN*HID
    _Float16* wt  = hB + (size_t)NN * HID;            // 3*128*128
    int*   degi    = (int*)(wt + 3 * 128 * 128);      // NN
    float* dinv    = (float*)(degi + NN);             // NN
    int*   rowptr  = (int*)(dinv + NN);               // NN+1
    int*   cursor  = rowptr + NN + 1;                 // NN
    int*   bsum    = cursor + NN;                     // 512
    int*   csr_off = bsum + 512;                      // NE

    const int TB = 256;
    const int nScanBlocks = (NN + 255) / 256;         // 391

    k_wprep<<<384, 128, 0, stream>>>(W1, W2, W3, wt);
    hipMemsetAsync(degi, 0, NN * sizeof(int), stream);
    k_degi      <<<(NE + TB - 1) / TB, TB, 0, stream>>>(colv, degi, NE);
    k_blocksum  <<<nScanBlocks, 256, 0, stream>>>(degi, dinv, bsum, NN);
    k_scan_bsum <<<1, 512, 0, stream>>>(bsum, nScanBlocks);
    k_scan_apply<<<nScanBlocks, 256, 0, stream>>>(degi, bsum, rowptr, cursor, NN);
    k_fill_csr  <<<(NE + TB - 1) / TB, TB, 0, stream>>>(row, colv, cursor, csr_off, NE);

    const int gemmBlocks = (NN + 127) / 128;          // 782
    const int aggBlocks  = (NN + 31) / 32;            // 3125

    // layer 1: hA = dinv*(x@W1)
    k_gemm<<<gemmBlocks, TB, 0, stream>>>(x, wt, dinv, hA, NN);
    // layer 2 fused: A = relu(agg(hA)+b1); hB = dinv*(A@W2)
    k_gemm_agg<<<gemmBlocks, 512, 0, stream>>>(hA, csr_off, rowptr, dinv, b1,
                                               wt + (1 << 14), hB, NN);
    // layer 3 fused: A = relu(agg(hB)+b2); hA = dinv*(A@W3)
    k_gemm_agg<<<gemmBlocks, 512, 0, stream>>>(hB, csr_off, rowptr, dinv, b2,
                                               wt + (2 << 14), hA, NN);
    // final: out = agg(hA) + b3, split by feature half (L2-capacity A/B probe)
    k_aggregate_h<0><<<aggBlocks, TB, 0, stream>>>(hA, csr_off, rowptr, dinv, b3, out, NN);
    k_aggregate_h<1><<<aggBlocks, TB, 0, stream>>>(hA, csr_off, rowptr, dinv, b3, out, NN);
}

// Round 13
// 237.114 us; speedup vs baseline: 1.1876x; 1.1876x over previous
//
#include <hip/hip_runtime.h>
#include <cstddef>

#define NN 100000
#define NE 600000
#define HID 128

typedef _Float16 half8 __attribute__((ext_vector_type(8)));
typedef _Float16 half2v __attribute__((ext_vector_type(2)));
typedef float f32x4 __attribute__((ext_vector_type(4)));

union H8 { _Float16 h[8]; half2v p[4]; uint4 u; half8 v; };

// shared accumulate helper: accf[0..7] += 8 f16 lanes of hh
__device__ __forceinline__ void acc8(const H8& hh, float* accf) {
#if __has_builtin(__builtin_amdgcn_fdot2)
    const half2v selx = {(_Float16)1.0f, (_Float16)0.0f};
    const half2v sely = {(_Float16)0.0f, (_Float16)1.0f};
    #pragma unroll
    for (int p = 0; p < 4; ++p) {
        accf[2*p]   = __builtin_amdgcn_fdot2(hh.p[p], selx, accf[2*p],   false);
        accf[2*p+1] = __builtin_amdgcn_fdot2(hh.p[p], sely, accf[2*p+1], false);
    }
#else
    #pragma unroll
    for (int j = 0; j < 8; ++j) accf[j] += (float)hh.h[j];
#endif
}

// ---------------------------------------------------------------- degree (int)
__global__ void k_degi(const int* __restrict__ col, int* __restrict__ degi, int E) {
    int e = blockIdx.x * blockDim.x + threadIdx.x;
    if (e < E) atomicAdd(&degi[col[e]], 1);
}

// ---------------------------------------------------------------- W -> WT f16
__global__ void k_wprep(const float* __restrict__ W1, const float* __restrict__ W2,
                        const float* __restrict__ W3, _Float16* __restrict__ wt) {
    int b = blockIdx.x;            // 0..383
    int layer = b >> 7, k = b & 127;
    const float* W = layer == 0 ? W1 : (layer == 1 ? W2 : W3);
    int c = threadIdx.x;           // 0..127
    wt[((size_t)layer << 14) + c * 128 + k] = (_Float16)W[k * 128 + c];
}

// ---------------------------------------------------------------- prefix scan
__global__ void k_blocksum(const int* __restrict__ degi, float* __restrict__ dinv,
                           int* __restrict__ bsum, int N) {
    __shared__ int sh[256];
    int i = blockIdx.x * 256 + threadIdx.x;
    int v = i < N ? degi[i] : 0;
    if (i < N) dinv[i] = v > 0 ? rsqrtf((float)v) : 0.0f;
    sh[threadIdx.x] = v;
    __syncthreads();
    for (int s = 128; s > 0; s >>= 1) {
        if (threadIdx.x < s) sh[threadIdx.x] += sh[threadIdx.x + s];
        __syncthreads();
    }
    if (threadIdx.x == 0) bsum[blockIdx.x] = sh[0];
}

__global__ void k_scan_bsum(int* __restrict__ bsum, int nb) {
    __shared__ int sh[512];
    int tid = threadIdx.x;
    int v = (tid < nb) ? bsum[tid] : 0;
    sh[tid] = v;
    __syncthreads();
    #pragma unroll
    for (int s = 1; s < 512; s <<= 1) {
        int t = (tid >= s) ? sh[tid - s] : 0;
        __syncthreads();
        sh[tid] += t;
        __syncthreads();
    }
    if (tid < nb) bsum[tid] = sh[tid] - v;   // exclusive
}

__global__ void k_scan_apply(const int* __restrict__ degi, const int* __restrict__ bsum,
                             int* __restrict__ rowptr, int* __restrict__ cursor, int N) {
    __shared__ int sh[256];
    int i = blockIdx.x * 256 + threadIdx.x;
    int v = (i < N) ? degi[i] : 0;
    sh[threadIdx.x] = v;
    __syncthreads();
    #pragma unroll
    for (int s = 1; s < 256; s <<= 1) {
        int t = (threadIdx.x >= s) ? sh[threadIdx.x - s] : 0;
        __syncthreads();
        sh[threadIdx.x] += t;
        __syncthreads();
    }
    if (i < N) {
        int excl = bsum[blockIdx.x] + sh[threadIdx.x] - v;
        rowptr[i] = excl;
        cursor[i] = excl;
        if (i == N - 1) rowptr[N] = bsum[blockIdx.x] + sh[threadIdx.x];
    }
}

// csr_off stores BYTE offset of the source row (src * HID * 2, fits int32)
__global__ void k_fill_csr(const int* __restrict__ row, const int* __restrict__ col,
                           int* __restrict__ cursor, int* __restrict__ csr_off, int E) {
    int e = blockIdx.x * blockDim.x + threadIdx.x;
    if (e >= E) return;
    int r = row[e], c = col[e];
    int pos = atomicAdd(&cursor[c], 1);
    csr_off[pos] = r * (HID * 2);
}

// ---------------------------------------------------------------- MFMA GEMM (layer 1)
// H[r] (f16) = dinv[r] * (A[r] @ W)
__global__ __launch_bounds__(256, 2) void k_gemm(
    const float* __restrict__ A, const _Float16* __restrict__ WT,
    const float* __restrict__ dinv, _Float16* __restrict__ H, int nrows)
{
    __shared__ _Float16 asl[128 * 128];   // 32 KB
    __shared__ _Float16 wsl[128 * 128];   // 32 KB
    const int tid  = threadIdx.x;
    const int lane = tid & 63;
    const int w    = tid >> 6;
    const int wm   = w >> 1, wn = w & 1;
    const int ln15 = lane & 15;
    const int hi   = lane >> 4;           // 0..3
    const int row0 = blockIdx.x * 128;

    #pragma unroll
    for (int i = 0; i < 8; ++i) {
        int g = i * 256 + tid;
        int c = g >> 4, k8 = (g & 15) << 3;
        uint4 wv = *(const uint4*)(WT + c * 128 + k8);
        *(uint4*)&wsl[c * 128 + (k8 ^ ((c & 7) << 3))] = wv;
    }
    #pragma unroll
    for (int i = 0; i < 8; ++i) {
        int g = i * 256 + tid;
        int r = g >> 4, c8 = (g & 15) << 3;
        int gr = row0 + r; if (gr >= nrows) gr = nrows - 1;
        const float4* src = (const float4*)(A + (size_t)gr * HID + c8);
        float4 v0 = src[0], v1 = src[1];
        H8 o;
        o.h[0] = (_Float16)v0.x; o.h[1] = (_Float16)v0.y;
        o.h[2] = (_Float16)v0.z; o.h[3] = (_Float16)v0.w;
        o.h[4] = (_Float16)v1.x; o.h[5] = (_Float16)v1.y;
        o.h[6] = (_Float16)v1.z; o.h[7] = (_Float16)v1.w;
        *(uint4*)&asl[r * 128 + (c8 ^ ((r & 7) << 3))] = o.u;
    }
    __syncthreads();

    f32x4 acc[4][4];
    #pragma unroll
    for (int i = 0; i < 4; ++i)
        #pragma unroll
        for (int j = 0; j < 4; ++j) {
            acc[i][j][0] = 0.0f; acc[i][j][1] = 0.0f;
            acc[i][j][2] = 0.0f; acc[i][j][3] = 0.0f;
        }

    #pragma unroll
    for (int ks = 0; ks < 4; ++ks) {
        const int k0 = ks * 32 + hi * 8;
        half8 a[4], b[4];
        #pragma unroll
        for (int i = 0; i < 4; ++i) {
            int ra = wm * 64 + i * 16 + ln15;
            a[i] = *(const half8*)&asl[ra * 128 + (k0 ^ ((ra & 7) << 3))];
            int cb = wn * 64 + i * 16 + ln15;
            b[i] = *(const half8*)&wsl[cb * 128 + (k0 ^ ((cb & 7) << 3))];
        }
        #pragma unroll
        for (int i = 0; i < 4; ++i)
            #pragma unroll
            for (int j = 0; j < 4; ++j)
                acc[i][j] = __builtin_amdgcn_mfma_f32_16x16x32_f16(a[i], b[j], acc[i][j], 0, 0, 0);
    }

    #pragma unroll
    for (int i = 0; i < 4; ++i) {
        #pragma unroll
        for (int q = 0; q < 4; ++q) {
            int r = row0 + wm * 64 + i * 16 + hi * 4 + q;
            if (r < nrows) {
                float s = dinv[r];
                #pragma unroll
                for (int j = 0; j < 4; ++j) {
                    H[(size_t)r * HID + wn * 64 + j * 16 + ln15] =
                        (_Float16)(acc[i][j][q] * s);
                }
            }
        }
    }
}

// ---------------------------------------------------------------- fused agg+GEMM (BM=64, 512 thr)
// A[r] = relu(dinv[r]*sum(hprev[src]) + bias); H[r] = dinv[r]*(A[r]@W)
// 48 KB LDS -> 3 blocks/CU -> 24 gather-waves/CU. Wave w gathers nodes
// w*8..w*8+7; MFMA: wave -> 16-row quad (wm=w>>1) x 64-col half (wn=w&1).
__global__ __launch_bounds__(512, 6) void k_gemm_agg(
    const _Float16* __restrict__ hprev, const int* __restrict__ csr_off,
    const int* __restrict__ rowptr, const float* __restrict__ dinv,
    const float* __restrict__ bias, const _Float16* __restrict__ WT,
    _Float16* __restrict__ H, int nrows)
{
    __shared__ _Float16 asl[64 * 128];    // 16 KB
    __shared__ _Float16 wsl[128 * 128];   // 32 KB
    __shared__ int s_ptr[65];
    const int tid  = threadIdx.x;
    const int lane = tid & 63;
    const int w    = tid >> 6;            // 0..7
    const int row0 = blockIdx.x * 64;

    if (tid < 65) {
        int n = row0 + tid; if (n > nrows) n = nrows;
        s_ptr[tid] = rowptr[n];
    }
    // stage W: 2048 uint4, 4/thread
    #pragma unroll
    for (int i = 0; i < 4; ++i) {
        int g = i * 512 + tid;
        int c = g >> 4, k8 = (g & 15) << 3;
        uint4 wv = *(const uint4*)(WT + c * 128 + k8);
        *(uint4*)&wsl[c * 128 + (k8 ^ ((c & 7) << 3))] = wv;
    }
    __syncthreads();

    const int es = lane >> 4;          // 0..3 edge slot (HIGH bits)
    const int fg = lane & 15;          // feature group
    const char* hb = (const char*)hprev;
    const int f0 = fg * 8 + es * 2;
    const float2 bv = *(const float2*)(bias + f0);
    const uint4 z = make_uint4(0, 0, 0, 0);

    #pragma unroll 2
    for (int t = 0; t < 8; ++t) {
        const int ni  = (w << 3) + t;
        const int beg = s_ptr[ni], end = s_ptr[ni + 1];

        float accf[8];
        #pragma unroll
        for (int j = 0; j < 8; ++j) accf[j] = 0.0f;

        int nr  = (end - beg + 3) >> 2;
        int idx = beg + es;
        int r   = 0;
        for (; r + 1 < nr; r += 2, idx += 8) {
            int o0 = (idx     < end) ? csr_off[idx]     : -1;
            int o1 = (idx + 4 < end) ? csr_off[idx + 4] : -1;
            uint4 u0 = (o0 >= 0) ? *(const uint4*)(hb + (size_t)(unsigned)o0 + fg * 16) : z;
            uint4 u1 = (o1 >= 0) ? *(const uint4*)(hb + (size_t)(unsigned)o1 + fg * 16) : z;
            H8 h0; h0.u = u0;
            H8 h1; h1.u = u1;
            acc8(h0, accf);
            acc8(h1, accf);
        }
        if (r < nr) {
            int o0 = (idx < end) ? csr_off[idx] : -1;
            uint4 u0 = (o0 >= 0) ? *(const uint4*)(hb + (size_t)(unsigned)o0 + fg * 16) : z;
            H8 h0; h0.u = u0;
            acc8(h0, accf);
        }

        #pragma unroll
        for (int j = 0; j < 8; ++j) {
            accf[j] += __shfl_xor(accf[j], 16);
            accf[j] += __shfl_xor(accf[j], 32);
        }

        float v0 = es < 2 ? (es == 0 ? accf[0] : accf[2])
                          : (es == 2 ? accf[4] : accf[6]);
        float v1 = es < 2 ? (es == 0 ? accf[1] : accf[3])
                          : (es == 2 ? accf[5] : accf[7]);
        int node = row0 + ni;
        float s = (node < nrows) ? dinv[node] : 0.0f;
        union { _Float16 h[2]; unsigned u; } o;
        o.h[0] = (_Float16)fmaxf(v0 * s + bv.x, 0.0f);
        o.h[1] = (_Float16)fmaxf(v1 * s + bv.y, 0.0f);
        *(unsigned*)&asl[ni * 128 + (((unsigned)(fg * 8)) ^ ((ni & 7) << 3)) + es * 2] = o.u;
    }
    __syncthreads();

    // MFMA: wave w -> rows [wm*16, wm*16+16), cols [wn*64, wn*64+64)
    const int wm   = w >> 1, wn = w & 1;
    const int ln15 = lane & 15;
    const int hi   = lane >> 4;

    f32x4 acc[4];
    #pragma unroll
    for (int j = 0; j < 4; ++j) {
        acc[j][0] = 0.0f; acc[j][1] = 0.0f;
        acc[j][2] = 0.0f; acc[j][3] = 0.0f;
    }

    #pragma unroll
    for (int ks = 0; ks < 4; ++ks) {
        const int k0 = ks * 32 + hi * 8;
        const int ra = wm * 16 + ln15;
        half8 a = *(const half8*)&asl[ra * 128 + (k0 ^ ((ra & 7) << 3))];
        half8 b[4];
        #pragma unroll
        for (int j = 0; j < 4; ++j) {
            int cb = wn * 64 + j * 16 + ln15;
            b[j] = *(const half8*)&wsl[cb * 128 + (k0 ^ ((cb & 7) << 3))];
        }
        #pragma unroll
        for (int j = 0; j < 4; ++j)
            acc[j] = __builtin_amdgcn_mfma_f32_16x16x32_f16(a, b[j], acc[j], 0, 0, 0);
    }

    #pragma unroll
    for (int q = 0; q < 4; ++q) {
        int r = row0 + wm * 16 + hi * 4 + q;
        if (r < nrows) {
            float s = dinv[r];
            #pragma unroll
            for (int j = 0; j < 4; ++j) {
                H[(size_t)r * HID + wn * 64 + j * 16 + ln15] =
                    (_Float16)(acc[j][q] * s);
            }
        }
    }
}

// ---------------------------------------------------------------- final aggregate
// out[node] (f32) = dinv[node] * sum(hprev[src]) + b3   (R9 structure, proven)
__global__ __launch_bounds__(256) void k_aggregate_f(
    const _Float16* __restrict__ hs, const int* __restrict__ csr_off,
    const int* __restrict__ rowptr, const float* __restrict__ dinv,
    const float* __restrict__ bias, float* __restrict__ out, int N)
{
    constexpr int NB = 32;
    constexpr int CAP = 2048;
    __shared__ int s_off[CAP + 8];
    __shared__ int s_ptr[NB + 1];

    const int tid = threadIdx.x;
    const int n0  = blockIdx.x * NB;   // 3125 * 32 == 100000 exactly
    if (tid <= NB) s_ptr[tid] = rowptr[n0 + tid];
    __syncthreads();
    const int Rbeg = s_ptr[0];
    const int cnt  = s_ptr[NB] - Rbeg;
    const bool fast = cnt <= CAP;
    if (fast) {
        for (int i = tid; i < cnt; i += 256) s_off[i] = csr_off[Rbeg + i];
    }
    __syncthreads();
    const int* offp = fast ? (const int*)s_off : (csr_off + Rbeg);

    const int lane = tid & 63;
    const int w    = tid >> 6;
    const int es   = lane >> 4;
    const int fg   = lane & 15;
    const char* hb = (const char*)hs;
    const int f0   = fg * 8 + es * 2;
    const float2 bv = *(const float2*)(bias + f0);
    const uint4 z = make_uint4(0, 0, 0, 0);

    #pragma unroll 2
    for (int t = 0; t < 8; ++t) {
        const int ni   = (w << 3) + t;
        const int node = n0 + ni;
        const int beg  = s_ptr[ni] - Rbeg;
        const int end  = s_ptr[ni + 1] - Rbeg;

        float accf[8];
        #pragma unroll
        for (int j = 0; j < 8; ++j) accf[j] = 0.0f;

        int nr  = (end - beg + 3) >> 2;
        int idx = beg + es;
        int r   = 0;
        for (; r + 1 < nr; r += 2, idx += 8) {
            int o0 = (idx     < end) ? offp[idx]     : -1;
            int o1 = (idx + 4 < end) ? offp[idx + 4] : -1;
            uint4 u0 = (o0 >= 0) ? *(const uint4*)(hb + (size_t)(unsigned)o0 + fg * 16) : z;
            uint4 u1 = (o1 >= 0) ? *(const uint4*)(hb + (size_t)(unsigned)o1 + fg * 16) : z;
            H8 h0; h0.u = u0;
            H8 h1; h1.u = u1;
            acc8(h0, accf);
            acc8(h1, accf);
        }
        if (r < nr) {
            int o0 = (idx < end) ? offp[idx] : -1;
            uint4 u0 = (o0 >= 0) ? *(const uint4*)(hb + (size_t)(unsigned)o0 + fg * 16) : z;
            H8 h0; h0.u = u0;
            acc8(h0, accf);
        }

        #pragma unroll
        for (int j = 0; j < 8; ++j) {
            accf[j] += __shfl_xor(accf[j], 16);
            accf[j] += __shfl_xor(accf[j], 32);
        }

        float v0 = es < 2 ? (es == 0 ? accf[0] : accf[2])
                          : (es == 2 ? accf[4] : accf[6]);
        float v1 = es < 2 ? (es == 0 ? accf[1] : accf[3])
                          : (es == 2 ? accf[5] : accf[7]);
        float s = dinv[node];
        v0 = v0 * s + bv.x;
        v1 = v1 * s + bv.y;
        *(float2*)(out + (size_t)node * HID + f0) = make_float2(v0, v1);
    }
}

// ---------------------------------------------------------------- launch
extern "C" void kernel_launch(void* const* d_in, const int* in_sizes, int n_in,
                              void* d_out, int out_size, void* d_ws, size_t ws_size,
                              hipStream_t stream)
{
    const float* x  = (const float*)d_in[0];
    const float* W1 = (const float*)d_in[1];
    const float* b1 = (const float*)d_in[2];
    const float* W2 = (const float*)d_in[3];
    const float* b2 = (const float*)d_in[4];
    const float* W3 = (const float*)d_in[5];
    const float* b3 = (const float*)d_in[6];
    const int*   ei = (const int*)d_in[7];
    const int* row  = ei;            // sources
    const int* colv = ei + NE;       // targets
    float* out = (float*)d_out;

    _Float16* hA  = (_Float16*)d_ws;                  // NN*HID
    _Float16* hB  = hA + (size_t)NN * HID;            // NN*HID
    _Float16* wt  = hB + (size_t)NN * HID;            // 3*128*128
    int*   degi    = (int*)(wt + 3 * 128 * 128);      // NN
    float* dinv    = (float*)(degi + NN);             // NN
    int*   rowptr  = (int*)(dinv + NN);               // NN+1
    int*   cursor  = rowptr + NN + 1;                 // NN
    int*   bsum    = cursor + NN;                     // 512
    int*   csr_off = bsum + 512;                      // NE

    const int TB = 256;
    const int nScanBlocks = (NN + 255) / 256;         // 391

    k_wprep<<<384, 128, 0, stream>>>(W1, W2, W3, wt);
    hipMemsetAsync(degi, 0, NN * sizeof(int), stream);
    k_degi      <<<(NE + TB - 1) / TB, TB, 0, stream>>>(colv, degi, NE);
    k_blocksum  <<<nScanBlocks, 256, 0, stream>>>(degi, dinv, bsum, NN);
    k_scan_bsum <<<1, 512, 0, stream>>>(bsum, nScanBlocks);
    k_scan_apply<<<nScanBlocks, 256, 0, stream>>>(degi, bsum, rowptr, cursor, NN);
    k_fill_csr  <<<(NE + TB - 1) / TB, TB, 0, stream>>>(row, colv, cursor, csr_off, NE);

    const int gemm1Blocks = (NN + 127) / 128;         // 782
    const int fusedBlocks = (NN + 63) / 64;           // 1563
    const int aggBlocks   = (NN + 31) / 32;           // 3125

    // layer 1: hA = dinv*(x@W1)
    k_gemm<<<gemm1Blocks, TB, 0, stream>>>(x, wt, dinv, hA, NN);
    // layer 2 fused: A = relu(agg(hA)+b1); hB = dinv*(A@W2)
    k_gemm_agg<<<fusedBlocks, 512, 0, stream>>>(hA, csr_off, rowptr, dinv, b1,
                                                wt + (1 << 14), hB, NN);
    // layer 3 fused: A = relu(agg(hB)+b2); hA = dinv*(A@W3)
    k_gemm_agg<<<fusedBlocks, 512, 0, stream>>>(hB, csr_off, rowptr, dinv, b2,
                                                wt + (2 << 14), hA, NN);
    // final: out = agg(hA) + b3
    k_aggregate_f<<<aggBlocks, TB, 0, stream>>>(hA, csr_off, rowptr, dinv, b3, out, NN);
}

// Round 14
// 233.734 us; speedup vs baseline: 1.2047x; 1.0145x over previous
//
#include <hip/hip_runtime.h>
#include <cstddef>

#define NN 100000
#define NE 600000
#define HID 128

typedef _Float16 half8 __attribute__((ext_vector_type(8)));
typedef _Float16 half2v __attribute__((ext_vector_type(2)));
typedef float f32x4 __attribute__((ext_vector_type(4)));

union H8 { _Float16 h[8]; half2v p[4]; uint4 u; half8 v; };

// shared accumulate helper: accf[0..7] += 8 f16 lanes of hh
__device__ __forceinline__ void acc8(const H8& hh, float* accf) {
#if __has_builtin(__builtin_amdgcn_fdot2)
    const half2v selx = {(_Float16)1.0f, (_Float16)0.0f};
    const half2v sely = {(_Float16)0.0f, (_Float16)1.0f};
    #pragma unroll
    for (int p = 0; p < 4; ++p) {
        accf[2*p]   = __builtin_amdgcn_fdot2(hh.p[p], selx, accf[2*p],   false);
        accf[2*p+1] = __builtin_amdgcn_fdot2(hh.p[p], sely, accf[2*p+1], false);
    }
#else
    #pragma unroll
    for (int j = 0; j < 8; ++j) accf[j] += (float)hh.h[j];
#endif
}

// ---------------------------------------------------------------- degree (int)
__global__ void k_degi(const int* __restrict__ col, int* __restrict__ degi, int E) {
    int e = blockIdx.x * blockDim.x + threadIdx.x;
    if (e < E) atomicAdd(&degi[col[e]], 1);
}

// ---------------------------------------------------------------- W -> WT f16
__global__ void k_wprep(const float* __restrict__ W1, const float* __restrict__ W2,
                        const float* __restrict__ W3, _Float16* __restrict__ wt) {
    int b = blockIdx.x;            // 0..383
    int layer = b >> 7, k = b & 127;
    const float* W = layer == 0 ? W1 : (layer == 1 ? W2 : W3);
    int c = threadIdx.x;           // 0..127
    wt[((size_t)layer << 14) + c * 128 + k] = (_Float16)W[k * 128 + c];
}

// ---------------------------------------------------------------- prefix scan
// block reduce degi -> bsum (raw block sums), and write dinv (fused)
__global__ void k_blocksum(const int* __restrict__ degi, float* __restrict__ dinv,
                           int* __restrict__ bsum, int N) {
    __shared__ int sh[256];
    int i = blockIdx.x * 256 + threadIdx.x;
    int v = i < N ? degi[i] : 0;
    if (i < N) dinv[i] = v > 0 ? rsqrtf((float)v) : 0.0f;
    sh[threadIdx.x] = v;
    __syncthreads();
    for (int s = 128; s > 0; s >>= 1) {
        if (threadIdx.x < s) sh[threadIdx.x] += sh[threadIdx.x + s];
        __syncthreads();
    }
    if (threadIdx.x == 0) bsum[blockIdx.x] = sh[0];
}

// merged: each block computes base = sum_{j<bid} bsum[j] itself, then the
// per-element inclusive scan (replaces the separate serial bsum scan)
__global__ void k_scan_apply(const int* __restrict__ degi, const int* __restrict__ bsum,
                             int* __restrict__ rowptr, int* __restrict__ cursor, int N) {
    __shared__ int sh[256];
    __shared__ int s_base;
    // base = exclusive prefix over block sums
    int partial = 0;
    for (int j = threadIdx.x; j < blockIdx.x; j += 256) partial += bsum[j];
    sh[threadIdx.x] = partial;
    __syncthreads();
    for (int s = 128; s > 0; s >>= 1) {
        if (threadIdx.x < s) sh[threadIdx.x] += sh[threadIdx.x + s];
        __syncthreads();
    }
    if (threadIdx.x == 0) s_base = sh[0];
    __syncthreads();

    int i = blockIdx.x * 256 + threadIdx.x;
    int v = (i < N) ? degi[i] : 0;
    sh[threadIdx.x] = v;
    __syncthreads();
    #pragma unroll
    for (int s = 1; s < 256; s <<= 1) {
        int t = (threadIdx.x >= s) ? sh[threadIdx.x - s] : 0;
        __syncthreads();
        sh[threadIdx.x] += t;
        __syncthreads();
    }
    if (i < N) {
        int excl = s_base + sh[threadIdx.x] - v;
        rowptr[i] = excl;
        cursor[i] = excl;
        if (i == N - 1) rowptr[N] = s_base + sh[threadIdx.x];
    }
}

// csr_off stores BYTE offset of the source row (src * HID * 2, fits int32)
__global__ void k_fill_csr(const int* __restrict__ row, const int* __restrict__ col,
                           int* __restrict__ cursor, int* __restrict__ csr_off, int E) {
    int e = blockIdx.x * blockDim.x + threadIdx.x;
    if (e >= E) return;
    int r = row[e], c = col[e];
    int pos = atomicAdd(&cursor[c], 1);
    csr_off[pos] = r * (HID * 2);
}

// ---------------------------------------------------------------- MFMA GEMM (layer 1)
// H[r] (f16) = dinv[r] * (A[r] @ W)
__global__ __launch_bounds__(256, 2) void k_gemm(
    const float* __restrict__ A, const _Float16* __restrict__ WT,
    const float* __restrict__ dinv, _Float16* __restrict__ H, int nrows)
{
    __shared__ _Float16 asl[128 * 128];   // 32 KB
    __shared__ _Float16 wsl[128 * 128];   // 32 KB
    const int tid  = threadIdx.x;
    const int lane = tid & 63;
    const int w    = tid >> 6;
    const int wm   = w >> 1, wn = w & 1;
    const int ln15 = lane & 15;
    const int hi   = lane >> 4;           // 0..3
    const int row0 = blockIdx.x * 128;

    #pragma unroll
    for (int i = 0; i < 8; ++i) {
        int g = i * 256 + tid;
        int c = g >> 4, k8 = (g & 15) << 3;
        uint4 wv = *(const uint4*)(WT + c * 128 + k8);
        *(uint4*)&wsl[c * 128 + (k8 ^ ((c & 7) << 3))] = wv;
    }
    #pragma unroll
    for (int i = 0; i < 8; ++i) {
        int g = i * 256 + tid;
        int r = g >> 4, c8 = (g & 15) << 3;
        int gr = row0 + r; if (gr >= nrows) gr = nrows - 1;
        const float4* src = (const float4*)(A + (size_t)gr * HID + c8);
        float4 v0 = src[0], v1 = src[1];
        H8 o;
        o.h[0] = (_Float16)v0.x; o.h[1] = (_Float16)v0.y;
        o.h[2] = (_Float16)v0.z; o.h[3] = (_Float16)v0.w;
        o.h[4] = (_Float16)v1.x; o.h[5] = (_Float16)v1.y;
        o.h[6] = (_Float16)v1.z; o.h[7] = (_Float16)v1.w;
        *(uint4*)&asl[r * 128 + (c8 ^ ((r & 7) << 3))] = o.u;
    }
    __syncthreads();

    f32x4 acc[4][4];
    #pragma unroll
    for (int i = 0; i < 4; ++i)
        #pragma unroll
        for (int j = 0; j < 4; ++j) {
            acc[i][j][0] = 0.0f; acc[i][j][1] = 0.0f;
            acc[i][j][2] = 0.0f; acc[i][j][3] = 0.0f;
        }

    #pragma unroll
    for (int ks = 0; ks < 4; ++ks) {
        const int k0 = ks * 32 + hi * 8;
        half8 a[4], b[4];
        #pragma unroll
        for (int i = 0; i < 4; ++i) {
            int ra = wm * 64 + i * 16 + ln15;
            a[i] = *(const half8*)&asl[ra * 128 + (k0 ^ ((ra & 7) << 3))];
            int cb = wn * 64 + i * 16 + ln15;
            b[i] = *(const half8*)&wsl[cb * 128 + (k0 ^ ((cb & 7) << 3))];
        }
        #pragma unroll
        for (int i = 0; i < 4; ++i)
            #pragma unroll
            for (int j = 0; j < 4; ++j)
                acc[i][j] = __builtin_amdgcn_mfma_f32_16x16x32_f16(a[i], b[j], acc[i][j], 0, 0, 0);
    }

    #pragma unroll
    for (int i = 0; i < 4; ++i) {
        #pragma unroll
        for (int q = 0; q < 4; ++q) {
            int r = row0 + wm * 64 + i * 16 + hi * 4 + q;
            if (r < nrows) {
                float s = dinv[r];
                #pragma unroll
                for (int j = 0; j < 4; ++j) {
                    H[(size_t)r * HID + wn * 64 + j * 16 + ln15] =
                        (_Float16)(acc[i][j][q] * s);
                }
            }
        }
    }
}

// ---------------------------------------------------------------- fused agg+GEMM (BM=32, 512 thr)
// A[r] = relu(dinv[r]*sum(hprev[src]) + bias); H[r] = dinv[r]*(A[r]@W)
// 40 KB LDS -> 4 blocks/CU -> 32 gather-waves/CU. Wave w gathers nodes
// w*4..w*4+3; MFMA: wave -> 16-row half (wm=w>>2) x 32-col quarter (wn=w&3).
__global__ __launch_bounds__(512, 8) void k_gemm_agg(
    const _Float16* __restrict__ hprev, const int* __restrict__ csr_off,
    const int* __restrict__ rowptr, const float* __restrict__ dinv,
    const float* __restrict__ bias, const _Float16* __restrict__ WT,
    _Float16* __restrict__ H, int nrows)
{
    __shared__ _Float16 asl[32 * 128];    // 8 KB
    __shared__ _Float16 wsl[128 * 128];   // 32 KB
    __shared__ int s_ptr[33];
    const int tid  = threadIdx.x;
    const int lane = tid & 63;
    const int w    = tid >> 6;            // 0..7
    const int row0 = blockIdx.x * 32;

    if (tid < 33) {
        int n = row0 + tid; if (n > nrows) n = nrows;
        s_ptr[tid] = rowptr[n];
    }
    // stage W: 2048 uint4, 4/thread
    #pragma unroll
    for (int i = 0; i < 4; ++i) {
        int g = i * 512 + tid;
        int c = g >> 4, k8 = (g & 15) << 3;
        uint4 wv = *(const uint4*)(WT + c * 128 + k8);
        *(uint4*)&wsl[c * 128 + (k8 ^ ((c & 7) << 3))] = wv;
    }
    __syncthreads();

    const int es = lane >> 4;          // 0..3 edge slot (HIGH bits)
    const int fg = lane & 15;          // feature group
    const char* hb = (const char*)hprev;
    const int f0 = fg * 8 + es * 2;
    const float2 bv = *(const float2*)(bias + f0);
    const uint4 z = make_uint4(0, 0, 0, 0);

    #pragma unroll 2
    for (int t = 0; t < 4; ++t) {
        const int ni  = (w << 2) + t;
        const int beg = s_ptr[ni], end = s_ptr[ni + 1];

        float accf[8];
        #pragma unroll
        for (int j = 0; j < 8; ++j) accf[j] = 0.0f;

        int nr  = (end - beg + 3) >> 2;
        int idx = beg + es;
        int r   = 0;
        for (; r + 1 < nr; r += 2, idx += 8) {
            int o0 = (idx     < end) ? csr_off[idx]     : -1;
            int o1 = (idx + 4 < end) ? csr_off[idx + 4] : -1;
            uint4 u0 = (o0 >= 0) ? *(const uint4*)(hb + (size_t)(unsigned)o0 + fg * 16) : z;
            uint4 u1 = (o1 >= 0) ? *(const uint4*)(hb + (size_t)(unsigned)o1 + fg * 16) : z;
            H8 h0; h0.u = u0;
            H8 h1; h1.u = u1;
            acc8(h0, accf);
            acc8(h1, accf);
        }
        if (r < nr) {
            int o0 = (idx < end) ? csr_off[idx] : -1;
            uint4 u0 = (o0 >= 0) ? *(const uint4*)(hb + (size_t)(unsigned)o0 + fg * 16) : z;
            H8 h0; h0.u = u0;
            acc8(h0, accf);
        }

        #pragma unroll
        for (int j = 0; j < 8; ++j) {
            accf[j] += __shfl_xor(accf[j], 16);
            accf[j] += __shfl_xor(accf[j], 32);
        }

        float v0 = es < 2 ? (es == 0 ? accf[0] : accf[2])
                          : (es == 2 ? accf[4] : accf[6]);
        float v1 = es < 2 ? (es == 0 ? accf[1] : accf[3])
                          : (es == 2 ? accf[5] : accf[7]);
        int node = row0 + ni;
        float s = (node < nrows) ? dinv[node] : 0.0f;
        union { _Float16 h[2]; unsigned u; } o;
        o.h[0] = (_Float16)fmaxf(v0 * s + bv.x, 0.0f);
        o.h[1] = (_Float16)fmaxf(v1 * s + bv.y, 0.0f);
        *(unsigned*)&asl[ni * 128 + (((unsigned)(fg * 8)) ^ ((ni & 7) << 3)) + es * 2] = o.u;
    }
    __syncthreads();

    // MFMA: wave w -> rows [wm*16, wm*16+16), cols [wn*32, wn*32+32)
    const int wm   = w >> 2, wn = w & 3;
    const int ln15 = lane & 15;
    const int hi   = lane >> 4;

    f32x4 acc[2];
    #pragma unroll
    for (int j = 0; j < 2; ++j) {
        acc[j][0] = 0.0f; acc[j][1] = 0.0f;
        acc[j][2] = 0.0f; acc[j][3] = 0.0f;
    }

    #pragma unroll
    for (int ks = 0; ks < 4; ++ks) {
        const int k0 = ks * 32 + hi * 8;
        const int ra = wm * 16 + ln15;
        half8 a = *(const half8*)&asl[ra * 128 + (k0 ^ ((ra & 7) << 3))];
        half8 b[2];
        #pragma unroll
        for (int j = 0; j < 2; ++j) {
            int cb = wn * 32 + j * 16 + ln15;
            b[j] = *(const half8*)&wsl[cb * 128 + (k0 ^ ((cb & 7) << 3))];
        }
        #pragma unroll
        for (int j = 0; j < 2; ++j)
            acc[j] = __builtin_amdgcn_mfma_f32_16x16x32_f16(a, b[j], acc[j], 0, 0, 0);
    }

    #pragma unroll
    for (int q = 0; q < 4; ++q) {
        int r = row0 + wm * 16 + hi * 4 + q;
        if (r < nrows) {
            float s = dinv[r];
            #pragma unroll
            for (int j = 0; j < 2; ++j) {
                H[(size_t)r * HID + wn * 32 + j * 16 + ln15] =
                    (_Float16)(acc[j][q] * s);
            }
        }
    }
}

// ---------------------------------------------------------------- final aggregate
// out[node] (f32) = dinv[node] * sum(hprev[src]) + b3   (R9 structure, proven)
__global__ __launch_bounds__(256) void k_aggregate_f(
    const _Float16* __restrict__ hs, const int* __restrict__ csr_off,
    const int* __restrict__ rowptr, const float* __restrict__ dinv,
    const float* __restrict__ bias, float* __restrict__ out, int N)
{
    constexpr int NB = 32;
    constexpr int CAP = 2048;
    __shared__ int s_off[CAP + 8];
    __shared__ int s_ptr[NB + 1];

    const int tid = threadIdx.x;
    const int n0  = blockIdx.x * NB;   // 3125 * 32 == 100000 exactly
    if (tid <= NB) s_ptr[tid] = rowptr[n0 + tid];
    __syncthreads();
    const int Rbeg = s_ptr[0];
    const int cnt  = s_ptr[NB] - Rbeg;
    const bool fast = cnt <= CAP;
    if (fast) {
        for (int i = tid; i < cnt; i += 256) s_off[i] = csr_off[Rbeg + i];
    }
    __syncthreads();
    const int* offp = fast ? (const int*)s_off : (csr_off + Rbeg);

    const int lane = tid & 63;
    const int w    = tid >> 6;
    const int es   = lane >> 4;
    const int fg   = lane & 15;
    const char* hb = (const char*)hs;
    const int f0   = fg * 8 + es * 2;
    const float2 bv = *(const float2*)(bias + f0);
    const uint4 z = make_uint4(0, 0, 0, 0);

    #pragma unroll 2
    for (int t = 0; t < 8; ++t) {
        const int ni   = (w << 3) + t;
        const int node = n0 + ni;
        const int beg  = s_ptr[ni] - Rbeg;
        const int end  = s_ptr[ni + 1] - Rbeg;

        float accf[8];
        #pragma unroll
        for (int j = 0; j < 8; ++j) accf[j] = 0.0f;

        int nr  = (end - beg + 3) >> 2;
        int idx = beg + es;
        int r   = 0;
        for (; r + 1 < nr; r += 2, idx += 8) {
            int o0 = (idx     < end) ? offp[idx]     : -1;
            int o1 = (idx + 4 < end) ? offp[idx + 4] : -1;
            uint4 u0 = (o0 >= 0) ? *(const uint4*)(hb + (size_t)(unsigned)o0 + fg * 16) : z;
            uint4 u1 = (o1 >= 0) ? *(const uint4*)(hb + (size_t)(unsigned)o1 + fg * 16) : z;
            H8 h0; h0.u = u0;
            H8 h1; h1.u = u1;
            acc8(h0, accf);
            acc8(h1, accf);
        }
        if (r < nr) {
            int o0 = (idx < end) ? offp[idx] : -1;
            uint4 u0 = (o0 >= 0) ? *(const uint4*)(hb + (size_t)(unsigned)o0 + fg * 16) : z;
            H8 h0; h0.u = u0;
            acc8(h0, accf);
        }

        #pragma unroll
        for (int j = 0; j < 8; ++j) {
            accf[j] += __shfl_xor(accf[j], 16);
            accf[j] += __shfl_xor(accf[j], 32);
        }

        float v0 = es < 2 ? (es == 0 ? accf[0] : accf[2])
                          : (es == 2 ? accf[4] : accf[6]);
        float v1 = es < 2 ? (es == 0 ? accf[1] : accf[3])
                          : (es == 2 ? accf[5] : accf[7]);
        float s = dinv[node];
        v0 = v0 * s + bv.x;
        v1 = v1 * s + bv.y;
        *(float2*)(out + (size_t)node * HID + f0) = make_float2(v0, v1);
    }
}

// ---------------------------------------------------------------- launch
extern "C" void kernel_launch(void* const* d_in, const int* in_sizes, int n_in,
                              void* d_out, int out_size, void* d_ws, size_t ws_size,
                              hipStream_t stream)
{
    const float* x  = (const float*)d_in[0];
    const float* W1 = (const float*)d_in[1];
    const float* b1 = (const float*)d_in[2];
    const float* W2 = (const float*)d_in[3];
    const float* b2 = (const float*)d_in[4];
    const float* W3 = (const float*)d_in[5];
    const float* b3 = (const float*)d_in[6];
    const int*   ei = (const int*)d_in[7];
    const int* row  = ei;            // sources
    const int* colv = ei + NE;       // targets
    float* out = (float*)d_out;

    _Float16* hA  = (_Float16*)d_ws;                  // NN*HID
    _Float16* hB  = hA + (size_t)NN * HID;            // NN*HID
    _Float16* wt  = hB + (size_t)NN * HID;            // 3*128*128
    int*   degi    = (int*)(wt + 3 * 128 * 128);      // NN
    float* dinv    = (float*)(degi + NN);             // NN
    int*   rowptr  = (int*)(dinv + NN);               // NN+1
    int*   cursor  = rowptr + NN + 1;                 // NN
    int*   bsum    = cursor + NN;                     // 512
    int*   csr_off = bsum + 512;                      // NE

    const int TB = 256;
    const int nScanBlocks = (NN + 255) / 256;         // 391

    k_wprep<<<384, 128, 0, stream>>>(W1, W2, W3, wt);
    hipMemsetAsync(degi, 0, NN * sizeof(int), stream);
    k_degi      <<<(NE + TB - 1) / TB, TB, 0, stream>>>(colv, degi, NE);
    k_blocksum  <<<nScanBlocks, 256, 0, stream>>>(degi, dinv, bsum, NN);
    k_scan_apply<<<nScanBlocks, 256, 0, stream>>>(degi, bsum, rowptr, cursor, NN);
    k_fill_csr  <<<(NE + TB - 1) / TB, TB, 0, stream>>>(row, colv, cursor, csr_off, NE);

    const int gemm1Blocks = (NN + 127) / 128;         // 782
    const int fusedBlocks = (NN + 31) / 32;           // 3125
    const int aggBlocks   = (NN + 31) / 32;           // 3125

    // layer 1: hA = dinv*(x@W1)
    k_gemm<<<gemm1Blocks, TB, 0, stream>>>(x, wt, dinv, hA, NN);
    // layer 2 fused: A = relu(agg(hA)+b1); hB = dinv*(A@W2)
    k_gemm_agg<<<fusedBlocks, 512, 0, stream>>>(hA, csr_off, rowptr, dinv, b1,
                                                wt + (1 << 14), hB, NN);
    // layer 3 fused: A = relu(agg(hB)+b2); hA = dinv*(A@W3)
    k_gemm_agg<<<fusedBlocks, 512, 0, stream>>>(hB, csr_off, rowptr, dinv, b2,
                                                wt + (2 << 14), hA, NN);
    // final: out = agg(hA) + b3
    k_aggregate_f<<<aggBlocks, TB, 0, stream>>>(hA, csr_off, rowptr, dinv, b3, out, NN);
}